// Round 1
// baseline (705.529 us; speedup 1.0000x reference)
//
#include <hip/hip_runtime.h>

// VQ nearest-code search + gather + loss, MFMA split-bf16 edition.
// z_real [32,1024,512] f32, z_imag same, embedding [4096,512] f32.
// N=32768 rows, D=512, K=4096.
// Outputs (flat f32): quantized (16777216) | z_imag (16777216) | loss (1).
//
// Distance argmin: s_k = 0.5||e_k||^2 - x.e_k. The dot is computed with
// 3-pass split-bf16 MFMA (hi*hi + hi*lo + lo*hi), error ~4e-5 vs typical
// min-gap ~8. Scratch for the bf16 splits lives INSIDE d_out (region is
// consumed by the gemm, then overwritten by the gather epilogue).
//
// This revision:
//  * T2 XOR-swizzle on the LDS tiles (both-sides: pre-swizzled global src
//    for the linear global_load_lds dest + matching XOR on ds_read_b128).
//    Old layout put each 16-lane read group in only 2 of 8 bank-slots
//    (SQ_LDS_BANK_CONFLICT 3.35e7); new layout spreads over all 8.
//  * Minimum 2-phase double-buffered pipeline: flattened (ktile,d-step)
//    loop, prefetch next step's tiles into the other 32KB LDS half BEFORE
//    this step's ds_read+MFMA, single __syncthreads per step (was 2).

#define NROWS 32768
#define DDIM  512
#define KCODES 4096
#define BM 128
#define BN 128
#define BK 32
#define KSPLIT 4
#define KPER (KCODES / KSPLIT)              // 1024 codes per k-split block
#define NSTEP ((KPER / BN) * (DDIM / BK))   // 8 ktiles * 16 d-steps = 128
#define TBUF (BM * BK)                      // u16 elements per LDS buffer

typedef short s16x8 __attribute__((ext_vector_type(8)));
typedef float f32x4 __attribute__((ext_vector_type(4)));
typedef unsigned long long u64;
typedef unsigned short u16;
typedef unsigned int u32;

__device__ __forceinline__ void glds16(const void* g, void* l) {
    __builtin_amdgcn_global_load_lds(
        (const __attribute__((address_space(1))) void*)g,
        (__attribute__((address_space(3))) void*)l, 16, 0, 0);
}

// float -> bf16 bits (RNE) + the value it rounds back to. Even if rounding
// differs slightly from HW, lo = bf16(x - hi) compensates (self-correcting).
__device__ __forceinline__ u16 f2bf(float x, float& back) {
    u32 b = __float_as_uint(x);
    u32 r = (b + 0x7fffu + ((b >> 16) & 1u)) >> 16;
    back = __uint_as_float(r << 16);
    return (u16)r;
}

// ------------------- K0: split fp32 -> bf16 hi/lo pair ----------------------
__global__ __launch_bounds__(256) void split_kernel(
    const float* __restrict__ src, u16* __restrict__ hi, u16* __restrict__ lo) {
    const size_t i = ((size_t)blockIdx.x * 256 + threadIdx.x) * 4;
    float4 v = *(const float4*)(src + i);
    ushort4 hv, lv;
    float bx, by, bz, bw;
    hv.x = f2bf(v.x, bx); hv.y = f2bf(v.y, by);
    hv.z = f2bf(v.z, bz); hv.w = f2bf(v.w, bw);
    float d;
    lv.x = f2bf(v.x - bx, d); lv.y = f2bf(v.y - by, d);
    lv.z = f2bf(v.z - bz, d); lv.w = f2bf(v.w - bw, d);
    *(ushort4*)(hi + i) = hv;
    *(ushort4*)(lo + i) = lv;
}

// ------------------------- K1: h[k] = 0.5*||e_k||^2 -------------------------
__global__ void enorm_kernel(const float* __restrict__ E, float* __restrict__ h) {
    const int k = blockIdx.x * 4 + (threadIdx.x >> 6);
    const int lane = threadIdx.x & 63;
    const float* row = E + (size_t)k * DDIM;
    float s = 0.f;
    #pragma unroll
    for (int d = 0; d < DDIM / 64; ++d) {
        float v = row[lane + d * 64];
        s += v * v;
    }
    #pragma unroll
    for (int off = 32; off; off >>= 1) s += __shfl_down(s, off, 64);
    if (lane == 0) h[k] = 0.5f * s;
}

// ------------- K2: MFMA score GEMM + fused running argmin -------------------
// grid = 256 row-blocks x 4 k-splits. Block: 256 thr = 4 waves (2x2),
// wave computes 64x64 of the 128x128 score tile via 4x4 16x16x32 MFMAs,
// 3 MFMA passes (hh, hl, lh) per fragment pair into one f32 accumulator.
// Flattened 128-step pipeline, double-buffered LDS, XOR-swizzled tiles.
__global__ __launch_bounds__(256, 2) void gemm_argmin_kernel(
    const u16* __restrict__ Xhi, const u16* __restrict__ Xlo,
    const u16* __restrict__ Ehi, const u16* __restrict__ Elo,
    const float* __restrict__ h, u64* __restrict__ packed) {
    __shared__ __align__(16) u16 smem[2 * 4 * TBUF];   // 2 halves x (Ahi|Alo|Bhi|Blo) = 64 KB
    __shared__ u64 red[BM][2];

    const int t = threadIdx.x;
    const int lane = t & 63;
    const int wid = t >> 6;
    const int wr = wid >> 1, wc = wid & 1;
    const int bx = blockIdx.x & 255;
    const int ks = blockIdx.x >> 8;
    const size_t rowBase = (size_t)bx * BM;
    const int kBase = ks * KPER;

    // wave wid stages buffer wid (wave-uniform LDS base, lane*16B linear dest)
    const u16* gsrc = (wid == 0) ? Xhi : (wid == 1) ? Xlo : (wid == 2) ? Ehi : Elo;
    const int lrow = lane >> 2;          // row within 16-row segment
    // XOR-swizzle (both-sides): the linear dest means 16B slot (lane&3) of
    // row r = seg*16 + (lane>>2). We place logical K-chunk
    // (lane&3) ^ ((r>>1)&3) there; (r>>1)&3 == (lane>>3)&3 for this pattern.
    const int lcol = (((lane & 3) ^ ((lane >> 3) & 3)) << 3);  // bf16-elem offset

    const int c = lane & 15, q = lane >> 4;
    // read side: logical chunk q of row m lives at slot q ^ ((m>>1)&3);
    // (m>>1)&3 == (c>>1)&3 for all fragment rows used below.
    const int qoff = ((q ^ ((c >> 1) & 3)) << 3);

    float best[16];
    u32 besti[16];
    #pragma unroll
    for (int i = 0; i < 16; ++i) { best[i] = 3.4e38f; besti[i] = 0; }

    f32x4 acc[4][4];

    // prologue: stage step 0 into half 0
    {
        const size_t gRow = (wid < 2) ? rowBase : (size_t)kBase;
        #pragma unroll
        for (int seg = 0; seg < 8; ++seg) {
            const u16* g = gsrc + (gRow + seg * 16 + lrow) * DDIM + lcol;
            glds16(g, smem + wid * TBUF + seg * 16 * BK);
        }
    }
    __syncthreads();

    auto step_fn = [&](const int s, const int half) {
        if ((s & 15) == 0) {
            #pragma unroll
            for (int i = 0; i < 4; ++i)
                #pragma unroll
                for (int j = 0; j < 4; ++j) acc[i][j] = f32x4{0.f, 0.f, 0.f, 0.f};
        }
        // prefetch step s+1 into the OTHER half; overlaps this step's compute,
        // drains at the end-of-step barrier (vmcnt(0) implied by syncthreads).
        if (s + 1 < NSTEP) {
            const int sn = s + 1;
            const size_t gRow = (wid < 2) ? rowBase
                                          : (size_t)(kBase + (sn >> 4) * BN);
            const int d0 = (sn & 15) * BK;
            u16* dst = smem + (half ^ 1) * (4 * TBUF) + wid * TBUF;
            #pragma unroll
            for (int seg = 0; seg < 8; ++seg) {
                const u16* g = gsrc + (gRow + seg * 16 + lrow) * DDIM + d0 + lcol;
                glds16(g, dst + seg * 16 * BK);
            }
        }
        const u16* base = smem + half * (4 * TBUF);
        s16x8 ah[4], al[4], bh[4], bl[4];
        #pragma unroll
        for (int i = 0; i < 4; ++i) {
            const int m = wr * 64 + i * 16 + c;
            const int n = wc * 64 + i * 16 + c;
            ah[i] = *(const s16x8*)(base + m * BK + qoff);
            al[i] = *(const s16x8*)(base + TBUF + m * BK + qoff);
            bh[i] = *(const s16x8*)(base + 2 * TBUF + n * BK + qoff);
            bl[i] = *(const s16x8*)(base + 3 * TBUF + n * BK + qoff);
        }
        #pragma unroll
        for (int i = 0; i < 4; ++i)
            #pragma unroll
            for (int j = 0; j < 4; ++j) {
                acc[i][j] = __builtin_amdgcn_mfma_f32_16x16x32_bf16(ah[i], bh[j], acc[i][j], 0, 0, 0);
                acc[i][j] = __builtin_amdgcn_mfma_f32_16x16x32_bf16(ah[i], bl[j], acc[i][j], 0, 0, 0);
                acc[i][j] = __builtin_amdgcn_mfma_f32_16x16x32_bf16(al[i], bh[j], acc[i][j], 0, 0, 0);
            }
        if ((s & 15) == 15) {
            // fold h, update running argmin. cols ascend (kt, then j) => strict
            // '<' keeps lowest index per lane; cross-lane ties in packed min.
            const int kt = (s >> 4) * BN;
            #pragma unroll
            for (int j = 0; j < 4; ++j) {
                const int col = kBase + kt + wc * 64 + j * 16 + c;
                const float hv = h[col];
                #pragma unroll
                for (int i = 0; i < 4; ++i)
                    #pragma unroll
                    for (int r = 0; r < 4; ++r) {
                        const float sc = hv - acc[i][j][r];
                        const int slot = i * 4 + r;
                        if (sc < best[slot]) { best[slot] = sc; besti[slot] = (u32)col; }
                    }
            }
        }
        __syncthreads();   // reads of 'half' done; prefetched half landed
    };

    for (int s = 0; s < NSTEP; s += 2) {
        step_fn(s, 0);       // compile-time LDS half at each call site
        step_fn(s + 1, 1);
    }

    // pack (score,idx); min over the 16 lanes of each quad (same rows)
    u64 p[16];
    #pragma unroll
    for (int i = 0; i < 16; ++i) {
        u32 ub = __float_as_uint(best[i]);
        ub = (ub & 0x80000000u) ? ~ub : (ub | 0x80000000u);
        p[i] = ((u64)ub << 32) | (u64)besti[i];
    }
    #pragma unroll
    for (int m = 1; m < 16; m <<= 1)
        #pragma unroll
        for (int i = 0; i < 16; ++i) {
            u64 o = __shfl_xor(p[i], m, 64);
            if (o < p[i]) p[i] = o;
        }
    if (c == 0) {
        #pragma unroll
        for (int i = 0; i < 16; ++i) {
            const int row = wr * 64 + (i >> 2) * 16 + q * 4 + (i & 3);
            red[row][wc] = p[i];
        }
    }
    __syncthreads();
    if (t < BM) {
        u64 a = red[t][0], b = red[t][1];
        packed[(rowBase + t) * KSPLIT + ks] = a < b ? a : b;
    }
}

// ----------------- K3: merge 4 k-split results -> final idx -----------------
__global__ void merge_kernel(const u64* __restrict__ packed, int* __restrict__ idx) {
    const int n = blockIdx.x * 256 + threadIdx.x;
    u64 m = packed[(size_t)n * 4];
    #pragma unroll
    for (int s = 1; s < 4; ++s) {
        u64 v = packed[(size_t)n * 4 + s];
        if (v < m) m = v;
    }
    idx[n] = (int)(u32)m;
}

// ---------- K4: gather quantized, copy z_imag, per-block loss partial -------
__global__ __launch_bounds__(256) void gather_kernel(
    const float* __restrict__ Zr, const float* __restrict__ Zi,
    const float* __restrict__ E, const int* __restrict__ idx,
    float* __restrict__ out, float* __restrict__ partials) {
    const int i = blockIdx.x * 256 + threadIdx.x;   // float4 index
    const size_t base = (size_t)i * 4;
    const int n = i >> 7;                 // 128 float4 per row
    const int d = (i & 127) << 2;
    const int k = idx[n];

    float4 qv = *(const float4*)(E + (size_t)k * DDIM + d);
    float4 z  = *(const float4*)(Zr + base);
    float4 zi = *(const float4*)(Zi + base);
    *(float4*)(out + base) = qv;
    *(float4*)(out + (size_t)NROWS * DDIM + base) = zi;

    const float dx = qv.x - z.x, dy = qv.y - z.y, dz = qv.z - z.z, dw = qv.w - z.w;
    float s = dx * dx + dy * dy + dz * dz + dw * dw;

    #pragma unroll
    for (int off = 32; off; off >>= 1) s += __shfl_down(s, off, 64);
    __shared__ float wred[4];
    const int lane = threadIdx.x & 63, wv = threadIdx.x >> 6;
    if (lane == 0) wred[wv] = s;
    __syncthreads();
    if (threadIdx.x == 0)
        partials[blockIdx.x] = wred[0] + wred[1] + wred[2] + wred[3];
}

// --------------------- K5: deterministic loss reduction ---------------------
__global__ void finalize_kernel(const float* __restrict__ partials,
                                float* __restrict__ out_loss) {
    __shared__ double red[256];
    double s = 0.0;
    for (int i = threadIdx.x; i < 16384; i += 256) s += (double)partials[i];
    red[threadIdx.x] = s;
    __syncthreads();
    for (int off = 128; off; off >>= 1) {
        if (threadIdx.x < off) red[threadIdx.x] += red[threadIdx.x + off];
        __syncthreads();
    }
    if (threadIdx.x == 0)
        *out_loss = (float)(1.25 * red[0] / 16777216.0);
}

extern "C" void kernel_launch(void* const* d_in, const int* in_sizes, int n_in,
                              void* d_out, int out_size, void* d_ws, size_t ws_size,
                              hipStream_t stream) {
    const float* z_real = (const float*)d_in[0];
    const float* z_imag = (const float*)d_in[1];
    const float* emb    = (const float*)d_in[2];
    float* out = (float*)d_out;
    char* outc = (char*)d_out;

    // Scratch INSIDE d_out (consumed before the gather overwrites it):
    //   region1 (quantized, 64 MB): Xhi 32 MB | Xlo 32 MB
    //   region2 (z_imag, 64 MB):    Ehi 4 MB | Elo 4 MB | h 16 KB | packed 1 MB
    u16* Xhi = (u16*)outc;
    u16* Xlo = (u16*)(outc + 33554432);
    char* reg2 = outc + 67108864;
    u16* Ehi = (u16*)reg2;
    u16* Elo = (u16*)(reg2 + 4194304);
    float* h = (float*)(reg2 + 8388608);
    u64* packed = (u64*)(reg2 + 8388608 + 16384);
    // ws: idx 128 KB | partials 64 KB  (196 KB total)
    int*   idx      = (int*)d_ws;
    float* partials = (float*)((char*)d_ws + 131072);

    split_kernel<<<16384, 256, 0, stream>>>(z_real, Xhi, Xlo);
    split_kernel<<<2048, 256, 0, stream>>>(emb, Ehi, Elo);
    enorm_kernel<<<KCODES / 4, 256, 0, stream>>>(emb, h);
    gemm_argmin_kernel<<<256 * KSPLIT, 256, 0, stream>>>(Xhi, Xlo, Ehi, Elo, h, packed);
    merge_kernel<<<NROWS / 256, 256, 0, stream>>>(packed, idx);
    gather_kernel<<<(NROWS * DDIM / 4) / 256, 256, 0, stream>>>(
        z_real, z_imag, emb, idx, out, partials);
    finalize_kernel<<<1, 256, 0, stream>>>(partials, out + (size_t)2 * NROWS * DDIM);
}

// Round 3
// 643.743 us; speedup vs baseline: 1.0960x; 1.0960x over previous
//
#include <hip/hip_runtime.h>

// VQ nearest-code search + gather + loss, MFMA split-bf16 edition.
// z_real [32,1024,512] f32, z_imag same, embedding [4096,512] f32.
// N=32768 rows, D=512, K=4096.
// Outputs (flat f32): quantized (16777216) | z_imag (16777216) | loss (1).
//
// Distance argmin: s_k = 0.5||e_k||^2 - x.e_k. The dot is computed with
// 3-pass split-bf16 MFMA (hi*hi + hi*lo + lo*hi), error ~4e-5 vs typical
// min-gap ~8. Scratch for the bf16 splits lives INSIDE d_out (region is
// consumed by the gemm, then overwritten by the gather epilogue).
//
// Round-3 revision: round 2 (BN=256) failed because the staging address
// double-counted the per-unit row offset (p[r] already includes it; the
// loop added r*16*DDIM again). Fixed: stage address is p[r] + d0 only.
// Structure otherwise identical to round 2:
//  * BN 256: per-wave output 64x128 (acc 4x8), 96 MFMA per barrier pair,
//    X-slab re-staged 4x instead of 8x.
//  * Proven 2-barrier-per-step schedule (round-1 2-phase pipeline was -20%).
//  * HW-verified zero-conflict XOR swizzle (pre-swizzled global src for
//    the linear global_load_lds dest + matching XOR on ds_read_b128).

#define NROWS 32768
#define DDIM  512
#define KCODES 4096
#define BM 128
#define BN 256
#define BK 32
#define KSPLIT 4
#define KPER (KCODES / KSPLIT)   // 1024 codes per k-split block

typedef short s16x8 __attribute__((ext_vector_type(8)));
typedef float f32x4 __attribute__((ext_vector_type(4)));
typedef unsigned long long u64;
typedef unsigned short u16;
typedef unsigned int u32;

__device__ __forceinline__ void glds16(const void* g, void* l) {
    __builtin_amdgcn_global_load_lds(
        (const __attribute__((address_space(1))) void*)g,
        (__attribute__((address_space(3))) void*)l, 16, 0, 0);
}

// float -> bf16 bits (RNE) + the value it rounds back to. Even if rounding
// differs slightly from HW, lo = bf16(x - hi) compensates (self-correcting).
__device__ __forceinline__ u16 f2bf(float x, float& back) {
    u32 b = __float_as_uint(x);
    u32 r = (b + 0x7fffu + ((b >> 16) & 1u)) >> 16;
    back = __uint_as_float(r << 16);
    return (u16)r;
}

// ------------------- K0: split fp32 -> bf16 hi/lo pair ----------------------
__global__ __launch_bounds__(256) void split_kernel(
    const float* __restrict__ src, u16* __restrict__ hi, u16* __restrict__ lo) {
    const size_t i = ((size_t)blockIdx.x * 256 + threadIdx.x) * 4;
    float4 v = *(const float4*)(src + i);
    ushort4 hv, lv;
    float bx, by, bz, bw;
    hv.x = f2bf(v.x, bx); hv.y = f2bf(v.y, by);
    hv.z = f2bf(v.z, bz); hv.w = f2bf(v.w, bw);
    float d;
    lv.x = f2bf(v.x - bx, d); lv.y = f2bf(v.y - by, d);
    lv.z = f2bf(v.z - bz, d); lv.w = f2bf(v.w - bw, d);
    *(ushort4*)(hi + i) = hv;
    *(ushort4*)(lo + i) = lv;
}

// ------------------------- K1: h[k] = 0.5*||e_k||^2 -------------------------
__global__ void enorm_kernel(const float* __restrict__ E, float* __restrict__ h) {
    const int k = blockIdx.x * 4 + (threadIdx.x >> 6);
    const int lane = threadIdx.x & 63;
    const float* row = E + (size_t)k * DDIM;
    float s = 0.f;
    #pragma unroll
    for (int d = 0; d < DDIM / 64; ++d) {
        float v = row[lane + d * 64];
        s += v * v;
    }
    #pragma unroll
    for (int off = 32; off; off >>= 1) s += __shfl_down(s, off, 64);
    if (lane == 0) h[k] = 0.5f * s;
}

// ------------- K2: MFMA score GEMM + fused running argmin -------------------
// grid = 256 row-blocks x 4 k-splits. Block: 256 thr = 4 waves (2x2),
// wave computes 64x128 of the 128x256 score tile via 4x8 16x16x32 MFMAs,
// 3 MFMA passes (hh, hl, lh) per fragment pair into one f32 accumulator.
// Proven 2-barrier-per-step schedule; 4 k-tiles x 16 d-steps = 64 steps.
__global__ __launch_bounds__(256, 2) void gemm_argmin_kernel(
    const u16* __restrict__ Xhi, const u16* __restrict__ Xlo,
    const u16* __restrict__ Ehi, const u16* __restrict__ Elo,
    const float* __restrict__ h, u64* __restrict__ packed) {
    // Contiguous buffers: Ahi[128][32] | Alo[128][32] | Bhi[256][32] | Blo[256][32]
    // = 48 KB. Unit u (of 48) = 16 rows = 512 u16 at smem + u*512.
    __shared__ __align__(16) u16 smem[24576];
    __shared__ u64 red[BM][2];

    const int t = threadIdx.x;
    const int lane = t & 63;
    const int wid = t >> 6;
    const int wr = wid >> 1, wc = wid & 1;
    const int bx = blockIdx.x & 255;
    const int ks = blockIdx.x >> 8;
    const size_t rowBase = (size_t)bx * BM;
    const int kBase = ks * KPER;

    const int lrow = lane >> 2;          // row within a 16-row unit
    // XOR-swizzle (both-sides, HW-verified conflict-free in round 1):
    // linear dest slot (lane&3) of row r holds logical chunk
    // (lane&3)^((r>>1)&3); (r>>1)&3 == (lane>>3)&3 for this mapping.
    const int chunk = (((lane & 3) ^ ((lane >> 3) & 3)) << 3);  // bf16-elem off

    // Per-wave staging pointer table: units u = wid*12 + r, r in [0,12).
    // u<8: Ahi<-Xhi rows u*16 ; u<16: Alo<-Xlo rows (u-8)*16 ;
    // u<32: Bhi<-Ehi rows (u-16)*16 ; else Blo<-Elo rows (u-32)*16.
    // p[r] includes the unit's row offset — stage address is p[r] + d0 ONLY.
    const u16* p[12];
    #pragma unroll
    for (int r = 0; r < 12; ++r) {
        const int u = wid * 12 + r;
        const u16* src = (u < 8) ? Xhi : (u < 16) ? Xlo : (u < 32) ? Ehi : Elo;
        const size_t grow = (u < 16) ? (rowBase + (size_t)(u & 7) * 16)
                                     : ((size_t)kBase + (size_t)((u - 16) & 15) * 16);
        p[r] = src + (grow + lrow) * DDIM + chunk;
    }
    u16* const sbase = smem + wid * (12 * 512);  // wave-uniform LDS dest base

    const int c = lane & 15, q = lane >> 4;
    // read side: logical chunk q of row m lives at slot q ^ ((m>>1)&3);
    // (m>>1)&3 == (c>>1)&3 for all fragment rows used below.
    const int qoff = ((q ^ ((c >> 1) & 3)) << 3);

    float best[16];
    u32 besti[16];
    #pragma unroll
    for (int i = 0; i < 16; ++i) { best[i] = 3.4e38f; besti[i] = 0; }

    for (int kt2 = 0; kt2 < KPER / BN; ++kt2) {       // 4 k-tiles of 256
        f32x4 acc[4][8];
        #pragma unroll
        for (int i = 0; i < 4; ++i)
            #pragma unroll
            for (int j = 0; j < 8; ++j) acc[i][j] = f32x4{0.f, 0.f, 0.f, 0.f};

        for (int d0 = 0; d0 < DDIM; d0 += BK) {
            __syncthreads();   // previous step's LDS reads done
            #pragma unroll
            for (int r = 0; r < 12; ++r)
                glds16(p[r] + d0, sbase + r * 512);
            __syncthreads();   // all buffers staged (vmcnt(0) implied)

            s16x8 ah[4], al[4];
            #pragma unroll
            for (int i = 0; i < 4; ++i) {
                const int m = wr * 64 + i * 16 + c;
                ah[i] = *(const s16x8*)(smem + m * BK + qoff);
                al[i] = *(const s16x8*)(smem + 4096 + m * BK + qoff);
            }
            #pragma unroll
            for (int j = 0; j < 8; ++j) {
                const int n = wc * 128 + j * 16 + c;
                const s16x8 bh = *(const s16x8*)(smem + 8192 + n * BK + qoff);
                const s16x8 bl = *(const s16x8*)(smem + 16384 + n * BK + qoff);
                #pragma unroll
                for (int i = 0; i < 4; ++i) {
                    acc[i][j] = __builtin_amdgcn_mfma_f32_16x16x32_bf16(ah[i], bh, acc[i][j], 0, 0, 0);
                    acc[i][j] = __builtin_amdgcn_mfma_f32_16x16x32_bf16(ah[i], bl, acc[i][j], 0, 0, 0);
                    acc[i][j] = __builtin_amdgcn_mfma_f32_16x16x32_bf16(al[i], bh, acc[i][j], 0, 0, 0);
                }
            }
        }
        // fold h, update running argmin. cols ascend (kt2, then j) => strict
        // '<' keeps lowest index per lane; cross-lane ties in packed min.
        #pragma unroll
        for (int j = 0; j < 8; ++j) {
            const int col = kBase + kt2 * BN + wc * 128 + j * 16 + c;
            const float hv = h[col];
            #pragma unroll
            for (int i = 0; i < 4; ++i)
                #pragma unroll
                for (int r = 0; r < 4; ++r) {
                    const float s = hv - acc[i][j][r];
                    const int slot = i * 4 + r;
                    if (s < best[slot]) { best[slot] = s; besti[slot] = (u32)col; }
                }
        }
        // advance B-side (E) staging pointers to the next 256-code tile
        #pragma unroll
        for (int r = 0; r < 12; ++r)
            if (wid * 12 + r >= 16) p[r] += (size_t)BN * DDIM;
    }

    // pack (score,idx); min over the 16 lanes of each quad (same rows)
    u64 p64[16];
    #pragma unroll
    for (int i = 0; i < 16; ++i) {
        u32 ub = __float_as_uint(best[i]);
        ub = (ub & 0x80000000u) ? ~ub : (ub | 0x80000000u);
        p64[i] = ((u64)ub << 32) | (u64)besti[i];
    }
    #pragma unroll
    for (int m = 1; m < 16; m <<= 1)
        #pragma unroll
        for (int i = 0; i < 16; ++i) {
            u64 o = __shfl_xor(p64[i], m, 64);
            if (o < p64[i]) p64[i] = o;
        }
    if (c == 0) {
        #pragma unroll
        for (int i = 0; i < 16; ++i) {
            const int row = wr * 64 + (i >> 2) * 16 + q * 4 + (i & 3);
            red[row][wc] = p64[i];
        }
    }
    __syncthreads();
    if (t < BM) {
        u64 a = red[t][0], b = red[t][1];
        packed[(rowBase + t) * KSPLIT + ks] = a < b ? a : b;
    }
}

// ----------------- K3: merge 4 k-split results -> final idx -----------------
__global__ void merge_kernel(const u64* __restrict__ packed, int* __restrict__ idx) {
    const int n = blockIdx.x * 256 + threadIdx.x;
    u64 m = packed[(size_t)n * 4];
    #pragma unroll
    for (int s = 1; s < 4; ++s) {
        u64 v = packed[(size_t)n * 4 + s];
        if (v < m) m = v;
    }
    idx[n] = (int)(u32)m;
}

// ---------- K4: gather quantized, copy z_imag, per-block loss partial -------
__global__ __launch_bounds__(256) void gather_kernel(
    const float* __restrict__ Zr, const float* __restrict__ Zi,
    const float* __restrict__ E, const int* __restrict__ idx,
    float* __restrict__ out, float* __restrict__ partials) {
    const int i = blockIdx.x * 256 + threadIdx.x;   // float4 index
    const size_t base = (size_t)i * 4;
    const int n = i >> 7;                 // 128 float4 per row
    const int d = (i & 127) << 2;
    const int k = idx[n];

    float4 qv = *(const float4*)(E + (size_t)k * DDIM + d);
    float4 z  = *(const float4*)(Zr + base);
    float4 zi = *(const float4*)(Zi + base);
    *(float4*)(out + base) = qv;
    *(float4*)(out + (size_t)NROWS * DDIM + base) = zi;

    const float dx = qv.x - z.x, dy = qv.y - z.y, dz = qv.z - z.z, dw = qv.w - z.w;
    float s = dx * dx + dy * dy + dz * dz + dw * dw;

    #pragma unroll
    for (int off = 32; off; off >>= 1) s += __shfl_down(s, off, 64);
    __shared__ float wred[4];
    const int lane = threadIdx.x & 63, wv = threadIdx.x >> 6;
    if (lane == 0) wred[wv] = s;
    __syncthreads();
    if (threadIdx.x == 0)
        partials[blockIdx.x] = wred[0] + wred[1] + wred[2] + wred[3];
}

// --------------------- K5: deterministic loss reduction ---------------------
__global__ void finalize_kernel(const float* __restrict__ partials,
                                float* __restrict__ out_loss) {
    __shared__ double red[256];
    double s = 0.0;
    for (int i = threadIdx.x; i < 16384; i += 256) s += (double)partials[i];
    red[threadIdx.x] = s;
    __syncthreads();
    for (int off = 128; off; off >>= 1) {
        if (threadIdx.x < off) red[threadIdx.x] += red[threadIdx.x + off];
        __syncthreads();
    }
    if (threadIdx.x == 0)
        *out_loss = (float)(1.25 * red[0] / 16777216.0);
}

extern "C" void kernel_launch(void* const* d_in, const int* in_sizes, int n_in,
                              void* d_out, int out_size, void* d_ws, size_t ws_size,
                              hipStream_t stream) {
    const float* z_real = (const float*)d_in[0];
    const float* z_imag = (const float*)d_in[1];
    const float* emb    = (const float*)d_in[2];
    float* out = (float*)d_out;
    char* outc = (char*)d_out;

    // Scratch INSIDE d_out (consumed before the gather overwrites it):
    //   region1 (quantized, 64 MB): Xhi 32 MB | Xlo 32 MB
    //   region2 (z_imag, 64 MB):    Ehi 4 MB | Elo 4 MB | h 16 KB | packed 1 MB
    u16* Xhi = (u16*)outc;
    u16* Xlo = (u16*)(outc + 33554432);
    char* reg2 = outc + 67108864;
    u16* Ehi = (u16*)reg2;
    u16* Elo = (u16*)(reg2 + 4194304);
    float* h = (float*)(reg2 + 8388608);
    u64* packed = (u64*)(reg2 + 8388608 + 16384);
    // ws: idx 128 KB | partials 64 KB  (196 KB total)
    int*   idx      = (int*)d_ws;
    float* partials = (float*)((char*)d_ws + 131072);

    split_kernel<<<16384, 256, 0, stream>>>(z_real, Xhi, Xlo);
    split_kernel<<<2048, 256, 0, stream>>>(emb, Ehi, Elo);
    enorm_kernel<<<KCODES / 4, 256, 0, stream>>>(emb, h);
    gemm_argmin_kernel<<<256 * KSPLIT, 256, 0, stream>>>(Xhi, Xlo, Ehi, Elo, h, packed);
    merge_kernel<<<NROWS / 256, 256, 0, stream>>>(packed, idx);
    gather_kernel<<<(NROWS * DDIM / 4) / 256, 256, 0, stream>>>(
        z_real, z_imag, emb, idx, out, partials);
    finalize_kernel<<<1, 256, 0, stream>>>(partials, out + (size_t)2 * NROWS * DDIM);
}